// Round 1
// baseline (169.026 us; speedup 1.0000x reference)
//
#include <hip/hip_runtime.h>
#include <stdint.h>

// Problem constants (reference: B,T,D=4,4096,1024; E,C,O=8,1024,512)
#define Bdim 4
#define Tdim 4096
#define Ddim 1024
#define Edim 8
#define Cdim 1024
#define Odim 512
#define KT 16  // K tiles of 64 (Ddim/64)

using bf16x8 = __attribute__((ext_vector_type(8))) __bf16;
using f32x4  = __attribute__((ext_vector_type(4))) float;

// round-to-nearest-even f32 -> bf16 (inputs finite; no NaN handling needed)
__device__ __forceinline__ unsigned short f2bf(float f) {
  unsigned int u = __float_as_uint(f);
  u += 0x7fffu + ((u >> 16) & 1u);
  return (unsigned short)(u >> 16);
}

// Single merged cast: [0,nx4) from x, [nx4,ntot4) from w.
__global__ void cast_f32_to_bf16(const float* __restrict__ xin,
                                 const float* __restrict__ win,
                                 unsigned short* __restrict__ outp,
                                 int nx4, int ntot4) {
  int i = blockIdx.x * blockDim.x + threadIdx.x;
  if (i >= ntot4) return;
  float4 v;
  if (i < nx4) v = reinterpret_cast<const float4*>(xin)[i];
  else         v = reinterpret_cast<const float4*>(win)[i - nx4];
  ushort4 o;
  o.x = f2bf(v.x); o.y = f2bf(v.y); o.z = f2bf(v.z); o.w = f2bf(v.w);
  reinterpret_cast<ushort4*>(outp)[i] = o;
}

// async global->LDS, 16B per lane; LDS dest is wave-uniform base (HW adds
// lane*16B). Global address is per-lane -> gather + swizzle friendly.
__device__ __forceinline__ void async_copy16(const unsigned short* g,
                                             unsigned short* l) {
  __builtin_amdgcn_global_load_lds(
      (__attribute__((address_space(1))) unsigned int*)g,
      (__attribute__((address_space(3))) unsigned int*)l, 16, 0, 0);
}

#define FENCE() asm volatile("" ::: "memory")
#define BAR()   do { FENCE(); __builtin_amdgcn_s_barrier(); FENCE(); } while (0)

// R5: 256x256 tile, 8 waves, 8-phase counted-vmcnt schedule (T3+T4), T5
// setprio, T2 XOR swizzle (linear gload_lds dest + pre-swizzled gather src),
// T1 XCD swizzle (e = bid&7 -> 1 expert / XCD).
// Per K-tile: 4 phases = 4 block-level C-quadrants (A-half x B-half):
//   p0:(A0,B0) reads af+bf0, stages A1(t+1)
//   p1:(A0,B1) reads bf1,    stages A0(t+2)   (A0(t) last read at p0 -> safe)
//   p2:(A1,B1) reads af',    stages B0(t+2)   (B0(t) last read at p0 -> safe)
//   p3:(A1,B0) reuses regs,  stages B1(t+2)   (B1(t) last read at p1 -> safe)
// One vmcnt(6) per tile at p3 (3 half-tiles = 6 loads in flight); every
// half-tile lands >=4 phases before its first ds_read -> gather latency
// hidden. Prologue stages 7 half-tiles then vmcnt(6). Tail: vmcnt(0) at
// kt==KT-2 (skipped stages shift the in-flight window).
__global__ __launch_bounds__(512) void moe_mfma_gemm(
    const unsigned short* __restrict__ xbf,   // (B,T,D) bf16
    const unsigned short* __restrict__ wbf,   // (E,O,D) bf16
    const int* __restrict__ idx,              // (B,E,C)
    const float* __restrict__ bias,           // (E,O)
    float* __restrict__ out) {                // (B,E,C,O) f32
  __shared__ __align__(16) unsigned short sA[2][256][64];  // 64 KiB
  __shared__ __align__(16) unsigned short sB[2][256][64];  // 64 KiB

  // XCD-aware decode: e fastest (XCD = e). 256 blocks = 1/CU.
  const int bid = blockIdx.x;
  const int e   = bid & 7;
  const int rr_ = bid >> 3;       // 0..31
  const int nt  = rr_ & 1;        // N tile (256 cols)
  const int mt  = (rr_ >> 1) & 3; // M tile (256 rows)
  const int bb  = rr_ >> 3;       // batch
  const int be  = bb * Edim + e;

  const int tid  = threadIdx.x;
  const int lane = tid & 63;
  const int wid  = tid >> 6;   // 0..7
  const int rw   = wid >> 2;   // 0..1: 64-row sub-block within the A half
  const int cw   = wid & 3;    // 0..3: 32-col sub-block within the B half

  // Staging: per half-tile (128 rows x 64 cols) each wave issues 2
  // global_load_lds of 1KB (8 rows each); wave w covers rows w*16..w*16+15.
  // Lane loads global k-chunk ((lane&7) ^ (lane>>3)) of its row (inverse of
  // the read-side XOR swizzle; LDS dest stays linear).
  const int rsub = lane >> 3;                 // 0..7, == row&7 of this lane
  const int kcol = ((lane & 7) ^ rsub) * 8;   // pre-swizzled source chunk

  const unsigned short* pA[2][2];  // [half][instr] gathered token rows
#pragma unroll
  for (int h = 0; h < 2; ++h)
#pragma unroll
    for (int i = 0; i < 2; ++i) {
      const int rr  = h * 128 + wid * 16 + i * 8 + rsub;  // tile row 0..255
      const int tok = idx[be * Cdim + mt * 256 + rr];
      pA[h][i] = xbf + ((size_t)(bb * Tdim + tok)) * Ddim + kcol;
    }
  const unsigned short* pB00 =
      wbf + ((size_t)(e * Odim + nt * 256 + wid * 16 + rsub)) * Ddim + kcol;
  // drain idx loads so manual vmcnt counts below see exactly our stages
  asm volatile("s_waitcnt vmcnt(0)" ::: "memory");

#define STAGE_A(slot, h, koff) do {                                          \
    async_copy16(pA[h][0] + (koff), &sA[slot][(h)*128 + wid*16    ][0]);     \
    async_copy16(pA[h][1] + (koff), &sA[slot][(h)*128 + wid*16 + 8][0]);     \
  } while (0)
#define STAGE_B(slot, h, koff) do {                                          \
    async_copy16(pB00 + (h)*131072 + (koff),                                 \
                 &sB[slot][(h)*128 + wid*16    ][0]);                        \
    async_copy16(pB00 + (h)*131072 + 8192 + (koff),                          \
                 &sB[slot][(h)*128 + wid*16 + 8][0]);                        \
  } while (0)

  // ---- prologue: 7 half-tiles = tile0 complete + A0,B0,B1 of tile1 ----
  STAGE_A(0, 0, 0);
  STAGE_B(0, 0, 0);
  STAGE_B(0, 1, 0);
  STAGE_A(0, 1, 0);
  STAGE_A(1, 0, 64);
  STAGE_B(1, 0, 64);
  STAGE_B(1, 1, 64);
  asm volatile("s_waitcnt vmcnt(6)" ::: "memory");  // tile0 landed
  __builtin_amdgcn_s_barrier();
  FENCE();

  const int fr  = lane & 15;   // fragment m/n index
  const int fkc = lane >> 4;   // fragment k-chunk (0..3)
  const int sw  = fr & 7;      // read-side XOR (== row&7)

  f32x4 acc[2][2][4][2];
#pragma unroll
  for (int a = 0; a < 2; ++a)
#pragma unroll
    for (int bq = 0; bq < 2; ++bq)
#pragma unroll
      for (int im = 0; im < 4; ++im)
#pragma unroll
        for (int in = 0; in < 2; ++in)
          acc[a][bq][im][in] = (f32x4){0.f, 0.f, 0.f, 0.f};

  bf16x8 af[4][2], bf0[2][2], bf1[2][2];

  for (int kt = 0; kt < KT; ++kt) {
    const int slot  = kt & 1;
    const int nslot = slot ^ 1;
    const int k1 = (kt + 1) * 64;
    const int k2 = (kt + 2) * 64;
    const bool g1 = (kt + 1 < KT);
    const bool g2 = (kt + 2 < KT);

    // ---- phase 0: quadrant (a=0,b=0); stage A1(kt+1) ----
#pragma unroll
    for (int im = 0; im < 4; ++im)
#pragma unroll
      for (int kk = 0; kk < 2; ++kk)
        af[im][kk] = *(const bf16x8*)
            &sA[slot][rw*64 + im*16 + fr][((kk*4 + fkc) ^ sw) * 8];
#pragma unroll
    for (int in = 0; in < 2; ++in)
#pragma unroll
      for (int kk = 0; kk < 2; ++kk)
        bf0[in][kk] = *(const bf16x8*)
            &sB[slot][cw*32 + in*16 + fr][((kk*4 + fkc) ^ sw) * 8];
    if (g1) STAGE_A(nslot, 1, k1);
    BAR();
    __builtin_amdgcn_s_setprio(1);
#pragma unroll
    for (int im = 0; im < 4; ++im)
#pragma unroll
      for (int in = 0; in < 2; ++in)
#pragma unroll
        for (int kk = 0; kk < 2; ++kk)
          acc[0][0][im][in] = __builtin_amdgcn_mfma_f32_16x16x32_bf16(
              af[im][kk], bf0[in][kk], acc[0][0][im][in], 0, 0, 0);
    __builtin_amdgcn_s_setprio(0);
    BAR();

    // ---- phase 1: quadrant (a=0,b=1); stage A0(kt+2) ----
#pragma unroll
    for (int in = 0; in < 2; ++in)
#pragma unroll
      for (int kk = 0; kk < 2; ++kk)
        bf1[in][kk] = *(const bf16x8*)
            &sB[slot][128 + cw*32 + in*16 + fr][((kk*4 + fkc) ^ sw) * 8];
    if (g2) STAGE_A(slot, 0, k2);
    BAR();
    __builtin_amdgcn_s_setprio(1);
#pragma unroll
    for (int im = 0; im < 4; ++im)
#pragma unroll
      for (int in = 0; in < 2; ++in)
#pragma unroll
        for (int kk = 0; kk < 2; ++kk)
          acc[0][1][im][in] = __builtin_amdgcn_mfma_f32_16x16x32_bf16(
              af[im][kk], bf1[in][kk], acc[0][1][im][in], 0, 0, 0);
    __builtin_amdgcn_s_setprio(0);
    BAR();

    // ---- phase 2: quadrant (a=1,b=1); stage B0(kt+2) ----
#pragma unroll
    for (int im = 0; im < 4; ++im)
#pragma unroll
      for (int kk = 0; kk < 2; ++kk)
        af[im][kk] = *(const bf16x8*)
            &sA[slot][128 + rw*64 + im*16 + fr][((kk*4 + fkc) ^ sw) * 8];
    if (g2) STAGE_B(slot, 0, k2);
    BAR();
    __builtin_amdgcn_s_setprio(1);
#pragma unroll
    for (int im = 0; im < 4; ++im)
#pragma unroll
      for (int in = 0; in < 2; ++in)
#pragma unroll
        for (int kk = 0; kk < 2; ++kk)
          acc[1][1][im][in] = __builtin_amdgcn_mfma_f32_16x16x32_bf16(
              af[im][kk], bf1[in][kk], acc[1][1][im][in], 0, 0, 0);
    __builtin_amdgcn_s_setprio(0);
    BAR();

    // ---- phase 3: quadrant (a=1,b=0); stage B1(kt+2); tile-boundary vmcnt
#pragma unroll
    for (int z = 0; z < 1; ++z) { }  // no ds_reads: af(a=1), bf0 reused
    if (g2) STAGE_B(slot, 1, k2);
    BAR();
    __builtin_amdgcn_s_setprio(1);
#pragma unroll
    for (int im = 0; im < 4; ++im)
#pragma unroll
      for (int in = 0; in < 2; ++in)
#pragma unroll
        for (int kk = 0; kk < 2; ++kk)
          acc[1][0][im][in] = __builtin_amdgcn_mfma_f32_16x16x32_bf16(
              af[im][kk], bf0[in][kk], acc[1][0][im][in], 0, 0, 0);
    __builtin_amdgcn_s_setprio(0);
    if (kt == KT - 2)      asm volatile("s_waitcnt vmcnt(0)" ::: "memory");
    else if (kt <  KT - 2) asm volatile("s_waitcnt vmcnt(6)" ::: "memory");
    BAR();
  }
#undef STAGE_A
#undef STAGE_B

  // Epilogue. C/D layout (verified m89/m91): col = lane&15, row = (lane>>4)*4 + reg.
  const int crow0 = (lane >> 4) * 4;
  float* outBase = out + (size_t)be * (Cdim * Odim)
                 + (size_t)(mt * 256) * Odim + nt * 256;
#pragma unroll
  for (int a = 0; a < 2; ++a)
#pragma unroll
    for (int im = 0; im < 4; ++im) {
      float* prow = outBase + (size_t)(a*128 + rw*64 + im*16 + crow0) * Odim;
#pragma unroll
      for (int bq = 0; bq < 2; ++bq)
#pragma unroll
        for (int in = 0; in < 2; ++in) {
          const int col  = bq*128 + cw*32 + in*16 + fr;
          const float bv = bias[e * Odim + nt * 256 + col];
          float* p = prow + col;
#pragma unroll
          for (int r4 = 0; r4 < 4; ++r4)
            p[(size_t)r4 * Odim] = acc[a][bq][im][in][r4] + bv;
        }
    }
}

extern "C" void kernel_launch(void* const* d_in, const int* in_sizes, int n_in,
                              void* d_out, int out_size, void* d_ws, size_t ws_size,
                              hipStream_t stream) {
  const float* x = (const float*)d_in[0];       // (B,T,D) f32
  const int* idx = (const int*)d_in[1];         // (B,E,C) i32
  const float* w = (const float*)d_in[2];       // (E,O,D) f32
  const float* bias = (const float*)d_in[3];    // (E,O) f32
  float* out = (float*)d_out;

  // Workspace: x_bf16 (32 MiB) then w_bf16 (8 MiB), contiguous
  unsigned short* xbf = (unsigned short*)d_ws;
  unsigned short* wbf = xbf + (size_t)Bdim * Tdim * Ddim;

  const int nx4 = Bdim * Tdim * Ddim / 4;               // 4,194,304
  const int ntot4 = nx4 + Edim * Odim * Ddim / 4;       // 5,242,880
  cast_f32_to_bf16<<<(ntot4 + 255) / 256, 256, 0, stream>>>(x, w, xbf, nx4, ntot4);

  // 32 (b,e) pairs x 4 M-tiles x 2 N-tiles = 256 blocks (1/CU), XCD-swizzled
  moe_mfma_gemm<<<256, 512, 0, stream>>>(xbf, wbf, idx, bias, out);
}

// Round 2
// 165.922 us; speedup vs baseline: 1.0187x; 1.0187x over previous
//
#include <hip/hip_runtime.h>
#include <stdint.h>

// Problem constants (reference: B,T,D=4,4096,1024; E,C,O=8,1024,512)
#define Bdim 4
#define Tdim 4096
#define Ddim 1024
#define Edim 8
#define Cdim 1024
#define Odim 512
#define KT 16  // K tiles of 64 (Ddim/64)

using bf16x8 = __attribute__((ext_vector_type(8))) __bf16;
using f32x4  = __attribute__((ext_vector_type(4))) float;

// round-to-nearest-even f32 -> bf16 (inputs finite; no NaN handling needed)
__device__ __forceinline__ unsigned short f2bf(float f) {
  unsigned int u = __float_as_uint(f);
  u += 0x7fffu + ((u >> 16) & 1u);
  return (unsigned short)(u >> 16);
}

// Single merged cast: [0,nx4) from x, [nx4,ntot4) from w.
__global__ void cast_f32_to_bf16(const float* __restrict__ xin,
                                 const float* __restrict__ win,
                                 unsigned short* __restrict__ outp,
                                 int nx4, int ntot4) {
  int i = blockIdx.x * blockDim.x + threadIdx.x;
  if (i >= ntot4) return;
  float4 v;
  if (i < nx4) v = reinterpret_cast<const float4*>(xin)[i];
  else         v = reinterpret_cast<const float4*>(win)[i - nx4];
  ushort4 o;
  o.x = f2bf(v.x); o.y = f2bf(v.y); o.z = f2bf(v.z); o.w = f2bf(v.w);
  reinterpret_cast<ushort4*>(outp)[i] = o;
}

// async global->LDS, 16B per lane; LDS dest is wave-uniform base (HW adds
// lane*16B). Global address is per-lane -> gather + swizzle friendly.
__device__ __forceinline__ void async_copy16(const unsigned short* g,
                                             unsigned short* l) {
  __builtin_amdgcn_global_load_lds(
      (__attribute__((address_space(1))) unsigned int*)g,
      (__attribute__((address_space(3))) unsigned int*)l, 16, 0, 0);
}

#define FENCE() asm volatile("" ::: "memory")
#define BAR()   do { FENCE(); __builtin_amdgcn_s_barrier(); FENCE(); } while (0)

// R6 = R5 (256x256, 8 waves, 4 quadrant-phases/K-tile, counted vmcnt(6),
// T5 setprio, T2 swizzle, T1 XCD swizzle) with the pipeline UN-POISONED:
// R5's dynamic slot index (sA[kt&1]) made every ds_read may-alias the
// outstanding global_load_lds DMAs -> LLVM's waitcnt inserter injected its
// own conservative vmcnt drains before each phase's reads (it cannot parse
// our inline-asm vmcnt(6)), collapsing the schedule to synchronous 2-phase
// behavior (measured 678 TF == m248's 2ph 666 TF, not its 8ph 848 TF).
// Fix: K-loop unrolled x2 (static phase->buffer mapping, as in the verified
// m201 template "2 K-tiles/iter") + LDS split into 8 DISTINCT named arrays
// so alias analysis proves every phase's ds_reads disjoint from every
// in-flight DMA -> no compiler-inserted drains; our per-tile vmcnt(6) is
// the only staging wait.
// Schedule per even tile t=2*it (odd tile symmetric, e<->o):
//   p0: read sA_e0+sB_e0, stage A1(t+1)->sA_o1
//   p1: read sB_e1,       stage A0(t+2)->sA_e0  (read-before-write in order)
//   p2: read sA_e1,       stage B0(t+2)->sB_e0
//   p3: (regs reused),    stage B1(t+2)->sB_e1, vmcnt(6) [tile t+1 landed]
__global__ __launch_bounds__(512) void moe_mfma_gemm(
    const unsigned short* __restrict__ xbf,   // (B,T,D) bf16
    const unsigned short* __restrict__ wbf,   // (E,O,D) bf16
    const int* __restrict__ idx,              // (B,E,C)
    const float* __restrict__ bias,           // (E,O)
    float* __restrict__ out) {                // (B,E,C,O) f32
  // 8 distinct objects (16 KiB each, 128 KiB total) so alias analysis can
  // prove ds_read vs LDS-DMA disjointness. [half][slot] naming: e=even tile,
  // o=odd tile; 0/1 = 128-row half of the 256-row (A) / 256-col (B) tile.
  __shared__ __align__(16) unsigned short sA_e0[128 * 64];
  __shared__ __align__(16) unsigned short sA_e1[128 * 64];
  __shared__ __align__(16) unsigned short sA_o0[128 * 64];
  __shared__ __align__(16) unsigned short sA_o1[128 * 64];
  __shared__ __align__(16) unsigned short sB_e0[128 * 64];
  __shared__ __align__(16) unsigned short sB_e1[128 * 64];
  __shared__ __align__(16) unsigned short sB_o0[128 * 64];
  __shared__ __align__(16) unsigned short sB_o1[128 * 64];

  // XCD-aware decode: e fastest (XCD = e). 256 blocks = 1/CU.
  const int bid = blockIdx.x;
  const int e   = bid & 7;
  const int rr_ = bid >> 3;       // 0..31
  const int nt  = rr_ & 1;        // N tile (256 cols)
  const int mt  = (rr_ >> 1) & 3; // M tile (256 rows)
  const int bb  = rr_ >> 3;       // batch
  const int be  = bb * Edim + e;

  const int tid  = threadIdx.x;
  const int lane = tid & 63;
  const int wid  = tid >> 6;   // 0..7
  const int rw   = wid >> 2;   // 0..1: 64-row sub-block within the A half
  const int cw   = wid & 3;    // 0..3: 32-col sub-block within the B half

  // Staging: per half-tile (128 rows x 64 cols) each wave issues 2
  // global_load_lds of 1KB (8 rows each); wave w covers rows w*16..w*16+15.
  // Lane loads global k-chunk ((lane&7) ^ (lane>>3)) of its row (inverse of
  // the read-side XOR swizzle; LDS dest stays linear).
  const int rsub = lane >> 3;                 // 0..7, == row&7 of this lane
  const int kcol = ((lane & 7) ^ rsub) * 8;   // pre-swizzled source chunk

  const unsigned short* pA[2][2];  // [half][instr] gathered token rows
#pragma unroll
  for (int h = 0; h < 2; ++h)
#pragma unroll
    for (int i = 0; i < 2; ++i) {
      const int rr  = h * 128 + wid * 16 + i * 8 + rsub;  // tile row 0..255
      const int tok = idx[be * Cdim + mt * 256 + rr];
      pA[h][i] = xbf + ((size_t)(bb * Tdim + tok)) * Ddim + kcol;
    }
  const unsigned short* pB00 =
      wbf + ((size_t)(e * Odim + nt * 256 + wid * 16 + rsub)) * Ddim + kcol;
  // drain idx loads so manual vmcnt counts below see exactly our stages
  asm volatile("s_waitcnt vmcnt(0)" ::: "memory");

#define STAGE_A_(h, dstArr, koff) do {                                       \
    async_copy16(pA[h][0] + (koff), &dstArr[wid * 16 * 64]);                 \
    async_copy16(pA[h][1] + (koff), &dstArr[(wid * 16 + 8) * 64]);           \
  } while (0)
#define STAGE_B_(h, dstArr, koff) do {                                       \
    async_copy16(pB00 + (h) * 131072 + (koff), &dstArr[wid * 16 * 64]);      \
    async_copy16(pB00 + (h) * 131072 + 8192 + (koff),                        \
                 &dstArr[(wid * 16 + 8) * 64]);                              \
  } while (0)

  // ---- prologue: 7 half-tiles = tile0 complete + A0,B0,B1 of tile1 ----
  STAGE_A_(0, sA_e0, 0);
  STAGE_B_(0, sB_e0, 0);
  STAGE_B_(1, sB_e1, 0);
  STAGE_A_(1, sA_e1, 0);
  STAGE_A_(0, sA_o0, 64);
  STAGE_B_(0, sB_o0, 64);
  STAGE_B_(1, sB_o1, 64);
  asm volatile("s_waitcnt vmcnt(6)" ::: "memory");  // tile0 (8 oldest) landed
  __builtin_amdgcn_s_barrier();
  FENCE();

  const int fr  = lane & 15;   // fragment m/n index
  const int fkc = lane >> 4;   // fragment k-chunk (0..3)
  const int sw  = fr & 7;      // read-side XOR (== row&7)

  f32x4 acc[2][2][4][2];
#pragma unroll
  for (int a = 0; a < 2; ++a)
#pragma unroll
    for (int bq = 0; bq < 2; ++bq)
#pragma unroll
      for (int im = 0; im < 4; ++im)
#pragma unroll
        for (int in = 0; in < 2; ++in)
          acc[a][bq][im][in] = (f32x4){0.f, 0.f, 0.f, 0.f};

  bf16x8 af[4][2], bf0[2][2], bf1[2][2];

#define LD_A(arr)                                                            \
  _Pragma("unroll")                                                          \
  for (int im = 0; im < 4; ++im)                                             \
    _Pragma("unroll")                                                        \
    for (int kk = 0; kk < 2; ++kk)                                           \
      af[im][kk] = *(const bf16x8*)&arr[(size_t)(rw * 64 + im * 16 + fr) * 64 \
                                        + (((kk * 4 + fkc) ^ sw) * 8)];
#define LD_B(arr, dst)                                                       \
  _Pragma("unroll")                                                          \
  for (int in = 0; in < 2; ++in)                                             \
    _Pragma("unroll")                                                        \
    for (int kk = 0; kk < 2; ++kk)                                           \
      dst[in][kk] = *(const bf16x8*)&arr[(size_t)(cw * 32 + in * 16 + fr) * 64 \
                                         + (((kk * 4 + fkc) ^ sw) * 8)];
#define MFMA16(aq, bq_, B_)                                                  \
  __builtin_amdgcn_s_setprio(1);                                             \
  _Pragma("unroll")                                                          \
  for (int im = 0; im < 4; ++im)                                             \
    _Pragma("unroll")                                                        \
    for (int in = 0; in < 2; ++in)                                           \
      _Pragma("unroll")                                                      \
      for (int kk = 0; kk < 2; ++kk)                                         \
        acc[aq][bq_][im][in] = __builtin_amdgcn_mfma_f32_16x16x32_bf16(      \
            af[im][kk], B_[in][kk], acc[aq][bq_][im][in], 0, 0, 0);          \
  __builtin_amdgcn_s_setprio(0);

  for (int it = 0; it < KT / 2; ++it) {
    const bool g2  = (it < 7);
    const int k1e = (2 * it + 1) * 64;
    const int k2e = (2 * it + 2) * 64;
    const int k1o = (2 * it + 2) * 64;
    const int k2o = (2 * it + 3) * 64;

    // ================= even tile t = 2*it (slot E) =================
    // p0: quadrant (0,0)
    LD_A(sA_e0);
    LD_B(sB_e0, bf0);
    STAGE_A_(1, sA_o1, k1e);          // A1(t+1), always valid (t+1 <= 15)
    BAR();
    MFMA16(0, 0, bf0);
    BAR();
    // p1: quadrant (0,1)
    LD_B(sB_e1, bf1);
    if (g2) STAGE_A_(0, sA_e0, k2e);  // A0(t+2); reads of sA_e0 precede this
    BAR();
    MFMA16(0, 1, bf1);
    BAR();
    // p2: quadrant (1,1)
    LD_A(sA_e1);
    if (g2) STAGE_B_(0, sB_e0, k2e);
    BAR();
    MFMA16(1, 1, bf1);
    BAR();
    // p3: quadrant (1,0); tile-boundary counted wait
    if (g2) STAGE_B_(1, sB_e1, k2e);
    BAR();
    MFMA16(1, 0, bf0);
    if (it == 7) asm volatile("s_waitcnt vmcnt(0)" ::: "memory");
    else         asm volatile("s_waitcnt vmcnt(6)" ::: "memory");
    BAR();

    // ================= odd tile t = 2*it+1 (slot O) =================
    // p0: quadrant (0,0)
    LD_A(sA_o0);
    LD_B(sB_o0, bf0);
    if (g2) STAGE_A_(1, sA_e1, k1o);  // A1(t+2) -> even slot half1
    BAR();
    MFMA16(0, 0, bf0);
    BAR();
    // p1: quadrant (0,1)
    LD_B(sB_o1, bf1);
    if (g2) STAGE_A_(0, sA_o0, k2o);  // A0(t+3)
    BAR();
    MFMA16(0, 1, bf1);
    BAR();
    // p2: quadrant (1,1)
    LD_A(sA_o1);
    if (g2) STAGE_B_(0, sB_o0, k2o);
    BAR();
    MFMA16(1, 1, bf1);
    BAR();
    // p3: quadrant (1,0); tile-boundary counted wait
    if (g2) STAGE_B_(1, sB_o1, k2o);
    BAR();
    MFMA16(1, 0, bf0);
    if (g2) asm volatile("s_waitcnt vmcnt(6)" ::: "memory");
    BAR();
  }
#undef STAGE_A_
#undef STAGE_B_
#undef LD_A
#undef LD_B
#undef MFMA16

  // Epilogue. C/D layout (verified m89/m91): col = lane&15, row = (lane>>4)*4 + reg.
  const int crow0 = (lane >> 4) * 4;
  float* outBase = out + (size_t)be * (Cdim * Odim)
                 + (size_t)(mt * 256) * Odim + nt * 256;
#pragma unroll
  for (int a = 0; a < 2; ++a)
#pragma unroll
    for (int im = 0; im < 4; ++im) {
      float* prow = outBase + (size_t)(a * 128 + rw * 64 + im * 16 + crow0) * Odim;
#pragma unroll
      for (int bq = 0; bq < 2; ++bq)
#pragma unroll
        for (int in = 0; in < 2; ++in) {
          const int col  = bq * 128 + cw * 32 + in * 16 + fr;
          const float bv = bias[e * Odim + nt * 256 + col];
          float* p = prow + col;
#pragma unroll
          for (int r4 = 0; r4 < 4; ++r4)
            p[(size_t)r4 * Odim] = acc[a][bq][im][in][r4] + bv;
        }
    }
}

extern "C" void kernel_launch(void* const* d_in, const int* in_sizes, int n_in,
                              void* d_out, int out_size, void* d_ws, size_t ws_size,
                              hipStream_t stream) {
  const float* x = (const float*)d_in[0];       // (B,T,D) f32
  const int* idx = (const int*)d_in[1];         // (B,E,C) i32
  const float* w = (const float*)d_in[2];       // (E,O,D) f32
  const float* bias = (const float*)d_in[3];    // (E,O) f32
  float* out = (float*)d_out;

  // Workspace: x_bf16 (32 MiB) then w_bf16 (8 MiB), contiguous
  unsigned short* xbf = (unsigned short*)d_ws;
  unsigned short* wbf = xbf + (size_t)Bdim * Tdim * Ddim;

  const int nx4 = Bdim * Tdim * Ddim / 4;               // 4,194,304
  const int ntot4 = nx4 + Edim * Odim * Ddim / 4;       // 5,242,880
  cast_f32_to_bf16<<<(ntot4 + 255) / 256, 256, 0, stream>>>(x, w, xbf, nx4, ntot4);

  // 32 (b,e) pairs x 4 M-tiles x 2 N-tiles = 256 blocks (1/CU), XCD-swizzled
  moe_mfma_gemm<<<256, 512, 0, stream>>>(xbf, wbf, idx, bias, out);
}